// Round 8
// baseline (187.770 us; speedup 1.0000x reference)
//
#include <hip/hip_runtime.h>
#include <cstddef>

#define BB 4
#define CC 512
#define NN 4096

using half8  = __attribute__((ext_vector_type(8))) _Float16;
using fp16x2 = __attribute__((ext_vector_type(2))) __fp16;
using short8 = __attribute__((ext_vector_type(8))) short;
using us8    = __attribute__((ext_vector_type(8))) unsigned short;
using f32x4  = __attribute__((ext_vector_type(4))) float;

__device__ __forceinline__ unsigned short f2bf(float x) {
    unsigned int u = __float_as_uint(x);
    u += 0x7fffu + ((u >> 16) & 1u);
    return (unsigned short)(u >> 16);
}

// ---------------- Kernel 0: weight conversion to fp16 ----------------
// Wc16 [192][512] = cat(Wf, Wg*log2e, Wh); Wv16 [512][64]
__global__ __launch_bounds__(256) void prep_kernel(
    const float* __restrict__ Wf, const float* __restrict__ Wg,
    const float* __restrict__ Wh, const float* __restrict__ Wv,
    _Float16* __restrict__ Wc16, _Float16* __restrict__ Wv16)
{
    int idx = blockIdx.x * 256 + threadIdx.x;
    int stride = gridDim.x * 256;
    const int N1 = 192 * 512, N2 = 512 * 64;
    for (int i = idx; i < N1 + N2; i += stride) {
        if (i < N1) {
            int row = i >> 9, c = i & 511;
            const float* src = (row < 64) ? Wf : ((row < 128) ? Wg : Wh);
            float sc = (row >= 64 && row < 128) ? 1.4426950408889634f : 1.0f;
            Wc16[i] = (_Float16)(sc * src[(row & 63) * 512 + c]);
        } else {
            int k = i - N1;
            Wv16[k] = (_Float16)Wv[k];
        }
    }
}

// ---------------- Kernel 1: projections f,g,h — LDS-staged fp16 MFMA ----------------
// grid 1024: (b, i-chunk of 16). Stage x[64c][16i] fp32 (db, reg prefetch),
// B-frags = 2x ds_read_b128 + cvt_pkrtz. A-frags from L2-hot Wc16.
// Kf[b][i][64], Qf[b][i][64] fp16; Vt[b][d][4096] bf16.
__global__ __launch_bounds__(256) void proj_kernel(
    const float* __restrict__ x, const _Float16* __restrict__ Wc16,
    _Float16* __restrict__ Kf, _Float16* __restrict__ Qf,
    unsigned short* __restrict__ Vt)
{
    __shared__ float xsT[2][16][68];   // [buf][i][c-chunk+pad]
    const int t    = threadIdx.x;
    const int w    = t >> 6;
    const int lane = t & 63;
    const int lh   = lane & 15;
    const int qd   = lane >> 4;
    const int b    = blockIdx.x >> 8;
    const int i0   = (blockIdx.x & 255) << 4;

    f32x4 acc[3];
    #pragma unroll
    for (int ot = 0; ot < 3; ot++) { acc[ot][0]=0.f; acc[ot][1]=0.f; acc[ot][2]=0.f; acc[ot][3]=0.f; }

    const int ti = t & 3;            // i-group (4 i per thread)
    const int tc = t >> 2;           // c-row 0..63
    const float* xbase = x + (size_t)b*CC*NN + i0 + ti*4;

    float4 st = *(const float4*)(xbase + (size_t)tc*NN);   // chunk 0
    xsT[0][ti*4+0][tc] = st.x; xsT[0][ti*4+1][tc] = st.y;
    xsT[0][ti*4+2][tc] = st.z; xsT[0][ti*4+3][tc] = st.w;
    __syncthreads();

    for (int ck = 0; ck < 8; ck++) {
        const int p = ck & 1;
        if (ck < 7) st = *(const float4*)(xbase + (size_t)((ck+1)*64 + tc)*NN);

        #pragma unroll
        for (int ks = 0; ks < 2; ks++) {
            half8 wf[3];
            #pragma unroll
            for (int ot = 0; ot < 3; ot++)
                wf[ot] = *(const half8*)(Wc16 + (size_t)(w*48 + ot*16 + lh)*512 + ck*64 + ks*32 + qd*8);
            const float* xr = &xsT[p][lh][ks*32 + qd*8];
            f32x4 xa = *(const f32x4*)xr;
            f32x4 xb = *(const f32x4*)(xr + 4);
            union { fp16x2 h2[4]; half8 h8; } u;
            u.h2[0] = __builtin_amdgcn_cvt_pkrtz(xa[0], xa[1]);
            u.h2[1] = __builtin_amdgcn_cvt_pkrtz(xa[2], xa[3]);
            u.h2[2] = __builtin_amdgcn_cvt_pkrtz(xb[0], xb[1]);
            u.h2[3] = __builtin_amdgcn_cvt_pkrtz(xb[2], xb[3]);
            #pragma unroll
            for (int ot = 0; ot < 3; ot++)
                acc[ot] = __builtin_amdgcn_mfma_f32_16x16x32_f16(wf[ot], u.h8, acc[ot], 0, 0, 0);
        }

        if (ck < 7) {   // store to other buffer; its readers finished before last barrier
            const int q = p ^ 1;
            xsT[q][ti*4+0][tc] = st.x; xsT[q][ti*4+1][tc] = st.y;
            xsT[q][ti*4+2][tc] = st.z; xsT[q][ti*4+3][tc] = st.w;
        }
        __syncthreads();
    }

    #pragma unroll
    for (int ot = 0; ot < 3; ot++) {
        int g16 = w*3 + ot;          // 0..11
        int m   = g16 >> 2;
        int obase = (g16 & 3)*16 + qd*4;
        int ig = i0 + lh;
        #pragma unroll
        for (int r = 0; r < 4; r++) {
            float v = acc[ot][r];
            int ol = obase + r;
            if (m == 0)       Kf[((size_t)b*NN + ig)*64 + ol] = (_Float16)v;
            else if (m == 1)  Qf[((size_t)b*NN + ig)*64 + ol] = (_Float16)v;
            else              Vt[((size_t)b*64 + ol)*NN + ig] = f2bf(v);
        }
    }
}

// ---------------- Kernel 2: split-K flash attention, single-buffer LDS K/V ----------------
// grid 1024: (b, j-tile 64, split s of 1024 keys = 8 chunks of 128).
// Register-carried prefetch of chunk c+1; 40 KB LDS -> 4 blocks/CU.
__global__ __launch_bounds__(256) void attn_kernel(
    const _Float16* __restrict__ Kf, const _Float16* __restrict__ Qf,
    const unsigned short* __restrict__ Vt,
    _Float16* __restrict__ Po16, float* __restrict__ Pl)
{
    __shared__ __align__(16) unsigned short Kbuf[128*64];  // [i][d] swizzled 16B blocks
    __shared__ __align__(16) unsigned short Vbuf[64*128];  // [d][i] swizzled 16B blocks
    __shared__ __align__(16) unsigned short Psh[4][16*64]; // per-wave P bf16

    const int t    = threadIdx.x;
    const int wv   = t >> 6;
    const int lane = t & 63;
    const int lh   = lane & 15;
    const int qd   = lane >> 4;

    const int B   = blockIdx.x;
    const int xcd = B & 7;
    const int rr  = B >> 3;
    const int b   = xcd >> 1;
    const int jt  = (rr & 31)*2 + (xcd & 1);
    const int s   = rr >> 5;
    const int j0  = (jt << 6) + wv*16;

    const unsigned short* Kfu = (const unsigned short*)Kf;

    half8 qf0, qf1;
    {
        const size_t qb = ((size_t)b*NN + j0 + lh)*64 + qd*8;
        qf0 = *(const half8*)(Qf + qb);
        qf1 = *(const half8*)(Qf + qb + 32);
    }

    f32x4 o_acc[4];
    float l_r[4];
    #pragma unroll
    for (int dt = 0; dt < 4; dt++) { o_acc[dt][0]=0.f; o_acc[dt][1]=0.f; o_acc[dt][2]=0.f; o_acc[dt][3]=0.f; }
    #pragma unroll
    for (int r = 0; r < 4; r++) l_r[r] = 0.f;

    const int koff = s*1024;
    const int ki = t >> 3, kc = t & 7;
    const int vd = t >> 4, vc = t & 15;

#define LOADC(ck) do {                                                        \
    size_t kg = ((size_t)b*NN + koff + (ck)*128)*64;                          \
    size_t vg = (size_t)b*64*NN + koff + (ck)*128;                            \
    _Pragma("unroll")                                                         \
    for (int r_ = 0; r_ < 4; r_++) {                                          \
        kst[r_] = *(const us8*)(Kfu + kg + (size_t)(r_*32 + ki)*64 + kc*8);   \
        vst[r_] = *(const us8*)(Vt  + vg + (size_t)(r_*16 + vd)*NN + vc*8);   \
    } } while (0)

#define STOREC() do {                                                         \
    _Pragma("unroll")                                                         \
    for (int r_ = 0; r_ < 4; r_++) {                                          \
        int i_ = r_*32 + ki;                                                  \
        int d_ = r_*16 + vd;                                                  \
        *(us8*)(&Kbuf[i_*64  + ((kc ^ (i_ & 7))*8)])  = kst[r_];              \
        *(us8*)(&Vbuf[d_*128 + ((vc ^ (d_ & 15))*8)]) = vst[r_];              \
    } } while (0)

    us8 kst[4], vst[4];
    LOADC(0);
    STOREC();
    __syncthreads();

    for (int ck = 0; ck < 8; ck++) {
        if (ck < 7) LOADC(ck + 1);

        #pragma unroll
        for (int half = 0; half < 2; half++) {
            const unsigned short* Kb = &Kbuf[half*64*64];
            const unsigned short* Vb = &Vbuf[0];

            f32x4 sc[4];
            #pragma unroll
            for (int it = 0; it < 4; it++) {
                sc[it][0]=0.f; sc[it][1]=0.f; sc[it][2]=0.f; sc[it][3]=0.f;
                const unsigned short* kr = Kb + (it*16 + lh)*64;
                half8 k0 = *(const half8*)(kr + ((qd     ^ (lh & 7))*8));
                half8 k1 = *(const half8*)(kr + (((4+qd) ^ (lh & 7))*8));
                sc[it] = __builtin_amdgcn_mfma_f32_16x16x32_f16(qf0, k0, sc[it], 0,0,0);
                sc[it] = __builtin_amdgcn_mfma_f32_16x16x32_f16(qf1, k1, sc[it], 0,0,0);
            }

            // logits pre-scaled by log2e (folded into Wg) -> exp2
            #pragma unroll
            for (int it = 0; it < 4; it++)
                #pragma unroll
                for (int r = 0; r < 4; r++) {
                    float p_ = exp2f(sc[it][r]);
                    l_r[r] += p_;
                    int i_ = it*16 + lh;
                    int j_ = qd*4 + r;
                    Psh[wv][j_*64 + (((i_>>3) ^ (j_ & 7))*8) + (i_ & 7)] = f2bf(p_);
                }
            asm volatile("s_waitcnt lgkmcnt(0)" ::: "memory");

            short8 pf0 = *(const short8*)&Psh[wv][lh*64 + ((qd     ^ (lh & 7))*8)];
            short8 pf1 = *(const short8*)&Psh[wv][lh*64 + (((4+qd) ^ (lh & 7))*8)];

            #pragma unroll
            for (int dt = 0; dt < 4; dt++) {
                const unsigned short* vr = Vb + (dt*16 + lh)*128;
                short8 v0 = *(const short8*)(vr + (((half*8 + qd    ) ^ lh)*8));
                short8 v1 = *(const short8*)(vr + (((half*8 + 4 + qd) ^ lh)*8));
                o_acc[dt] = __builtin_amdgcn_mfma_f32_16x16x32_bf16(pf0, v0, o_acc[dt], 0,0,0);
                o_acc[dt] = __builtin_amdgcn_mfma_f32_16x16x32_bf16(pf1, v1, o_acc[dt], 0,0,0);
            }
        }

        __syncthreads();              // all reads of Kbuf/Vbuf done
        if (ck < 7) STOREC();
        __syncthreads();              // stores visible
    }
#undef LOADC
#undef STOREC

    float inv[4];
    #pragma unroll
    for (int r = 0; r < 4; r++) {
        float l = l_r[r];
        #pragma unroll
        for (int off = 1; off < 16; off <<= 1)
            l += __shfl_xor(l, off);
        l_r[r] = l;
        inv[r] = 1.0f / l;
    }
    const size_t pbase = ((size_t)(s*4 + b)*NN + j0);
    #pragma unroll
    for (int dt = 0; dt < 4; dt++)
        #pragma unroll
        for (int r = 0; r < 4; r++)
            Po16[(pbase + qd*4 + r)*64 + dt*16 + lh] = (_Float16)(o_acc[dt][r] * inv[r]);
    if (lh == 0) {
        #pragma unroll
        for (int r = 0; r < 4; r++)
            Pl[pbase + qd*4 + r] = l_r[r];
    }
}

// ---------------- Kernel 3: fused combine + output projection + residual ----------------
// grid 512: (b, j-chunk of 32). Merges split-K partials inline while building sa frags.
__global__ __launch_bounds__(256) void outproj_kernel(
    const _Float16* __restrict__ Po16, const float* __restrict__ Pl,
    const _Float16* __restrict__ Wv16,
    const float* __restrict__ x, const float* __restrict__ gamma,
    float* __restrict__ out1, float* __restrict__ out2)
{
    const int t    = threadIdx.x;
    const int w    = t >> 6;
    const int lane = t & 63;
    const int lh   = lane & 15;
    const int qd   = lane >> 4;
    const int b    = blockIdx.x >> 7;
    const int j0   = (blockIdx.x & 127) << 5;
    const float g  = gamma[0];

    half8 sb[2][2];
    #pragma unroll
    for (int jt2 = 0; jt2 < 2; jt2++) {
        const int j = j0 + jt2*16 + lh;
        float os[16];
        #pragma unroll
        for (int k = 0; k < 16; k++) os[k] = 0.f;
        float lsum = 0.f;
        #pragma unroll
        for (int s = 0; s < 4; s++) {
            size_t base = ((size_t)(s*4 + b)*NN + j);
            half8 v0 = *(const half8*)(Po16 + base*64 + qd*8);
            half8 v1 = *(const half8*)(Po16 + base*64 + qd*8 + 32);
            float l = Pl[base];
            #pragma unroll
            for (int k = 0; k < 8; k++) {
                os[k]   = fmaf(l, (float)v0[k], os[k]);
                os[8+k] = fmaf(l, (float)v1[k], os[8+k]);
            }
            lsum += l;
        }
        float inv = 1.0f / lsum;
        union { fp16x2 h2[4]; half8 h8; } u0, u1;
        #pragma unroll
        for (int k = 0; k < 4; k++) {
            u0.h2[k] = __builtin_amdgcn_cvt_pkrtz(os[2*k]*inv,   os[2*k+1]*inv);
            u1.h2[k] = __builtin_amdgcn_cvt_pkrtz(os[8+2*k]*inv, os[8+2*k+1]*inv);
        }
        sb[jt2][0] = u0.h8;
        sb[jt2][1] = u1.h8;
    }

    #pragma unroll 2
    for (int ot8 = 0; ot8 < 8; ot8++) {
        const int ot = w*8 + ot8;
        const size_t wbase = (size_t)(ot*16 + lh)*64 + qd*8;
        half8 a0 = *(const half8*)(Wv16 + wbase);
        half8 a1 = *(const half8*)(Wv16 + wbase + 32);
        #pragma unroll
        for (int jt2 = 0; jt2 < 2; jt2++) {
            f32x4 acc; acc[0]=0.f; acc[1]=0.f; acc[2]=0.f; acc[3]=0.f;
            acc = __builtin_amdgcn_mfma_f32_16x16x32_f16(a0, sb[jt2][0], acc, 0, 0, 0);
            acc = __builtin_amdgcn_mfma_f32_16x16x32_f16(a1, sb[jt2][1], acc, 0, 0, 0);
            const int jg = j0 + jt2*16 + lh;
            #pragma unroll
            for (int r = 0; r < 4; r++) {
                const int o = ot*16 + qd*4 + r;
                size_t idx = ((size_t)b*CC + o)*NN + jg;
                float v = acc[r];
                out2[idx] = v;
                out1[idx] = fmaf(g, v, x[idx]);
            }
        }
    }
}

extern "C" void kernel_launch(void* const* d_in, const int* in_sizes, int n_in,
                              void* d_out, int out_size, void* d_ws, size_t ws_size,
                              hipStream_t stream) {
    const float* x     = (const float*)d_in[0];
    const float* Wf    = (const float*)d_in[1];
    const float* Wg    = (const float*)d_in[2];
    const float* Wh    = (const float*)d_in[3];
    const float* Wv    = (const float*)d_in[4];
    const float* gamma = (const float*)d_in[5];

    float* out1 = (float*)d_out;
    float* out2 = out1 + (size_t)BB*CC*NN;

    const size_t BND = (size_t)BB*NN*64;   // 1M elements
    char* wp = (char*)d_ws;
    _Float16*       Kf   = (_Float16*)wp;        wp += BND*2;   // 2 MB
    _Float16*       Qf   = (_Float16*)wp;        wp += BND*2;   // 2 MB
    unsigned short* Vt   = (unsigned short*)wp;  wp += BND*2;   // 2 MB
    _Float16*       Po16 = (_Float16*)wp;        wp += BND*4*2; // 8 MB (4 splits)
    float*          Pl   = (float*)wp;           wp += (size_t)4*BB*NN*4;  // 256 KB
    _Float16*       Wc16 = (_Float16*)wp;        wp += (size_t)192*512*2;
    _Float16*       Wv16 = (_Float16*)wp;

    prep_kernel<<<dim3(64), dim3(256), 0, stream>>>(Wf, Wg, Wh, Wv, Wc16, Wv16);
    proj_kernel<<<dim3(BB*256), dim3(256), 0, stream>>>(x, Wc16, Kf, Qf, Vt);
    attn_kernel<<<dim3(BB*256), dim3(256), 0, stream>>>(Kf, Qf, Vt, Po16, Pl);
    outproj_kernel<<<dim3(512), dim3(256), 0, stream>>>(Po16, Pl, Wv16, x, gamma, out1, out2);
}

// Round 9
// 172.084 us; speedup vs baseline: 1.0912x; 1.0912x over previous
//
#include <hip/hip_runtime.h>
#include <cstddef>

#define BB 4
#define CC 512
#define NN 4096

using half8  = __attribute__((ext_vector_type(8))) _Float16;
using fp16x2 = __attribute__((ext_vector_type(2))) __fp16;
using short8 = __attribute__((ext_vector_type(8))) short;
using us8    = __attribute__((ext_vector_type(8))) unsigned short;
using f32x4  = __attribute__((ext_vector_type(4))) float;

__device__ __forceinline__ unsigned short f2bf(float x) {
    unsigned int u = __float_as_uint(x);
    u += 0x7fffu + ((u >> 16) & 1u);
    return (unsigned short)(u >> 16);
}

// ---------------- Kernel 0: weight conversion to fp16 ----------------
// Wc16 [192][512] = cat(Wf, Wg*log2e, Wh); Wv16 [512][64]
__global__ __launch_bounds__(256) void prep_kernel(
    const float* __restrict__ Wf, const float* __restrict__ Wg,
    const float* __restrict__ Wh, const float* __restrict__ Wv,
    _Float16* __restrict__ Wc16, _Float16* __restrict__ Wv16)
{
    int idx = blockIdx.x * 256 + threadIdx.x;
    int stride = gridDim.x * 256;
    const int N1 = 192 * 512, N2 = 512 * 64;
    for (int i = idx; i < N1 + N2; i += stride) {
        if (i < N1) {
            int row = i >> 9, c = i & 511;
            const float* src = (row < 64) ? Wf : ((row < 128) ? Wg : Wh);
            float sc = (row >= 64 && row < 128) ? 1.4426950408889634f : 1.0f;
            Wc16[i] = (_Float16)(sc * src[(row & 63) * 512 + c]);
        } else {
            int k = i - N1;
            Wv16[k] = (_Float16)Wv[k];
        }
    }
}

// ---------------- Kernel 1: projections f,g,h — LDS-staged fp16 MFMA ----------------
// grid 512: (b, i-chunk of 32). x tile [64c][32i] fp32 double-buffered in LDS,
// register prefetch of x AND weights one chunk ahead. 2 MFMA per weight load.
__global__ __launch_bounds__(256) void proj_kernel(
    const float* __restrict__ x, const _Float16* __restrict__ Wc16,
    _Float16* __restrict__ Kf, _Float16* __restrict__ Qf,
    unsigned short* __restrict__ Vt)
{
    __shared__ float xsT[2][32][68];   // [buf][i][c] (68: 16B-aligned rows, pad)
    const int t    = threadIdx.x;
    const int w    = t >> 6;
    const int lane = t & 63;
    const int lh   = lane & 15;
    const int qd   = lane >> 4;
    const int b    = blockIdx.x >> 7;
    const int i0   = (blockIdx.x & 127) << 5;

    f32x4 acc[3][2];
    #pragma unroll
    for (int ot = 0; ot < 3; ot++)
        #pragma unroll
        for (int it = 0; it < 2; it++) { acc[ot][it][0]=0.f; acc[ot][it][1]=0.f; acc[ot][it][2]=0.f; acc[ot][it][3]=0.f; }

    const int ti8 = t & 7;           // i-group of 4
    const int tc2 = t >> 3;          // c-row 0..31
    const float* xbase = x + (size_t)b*CC*NN + i0 + ti8*4;
    const _Float16* wbase = Wc16 + (size_t)(w*48 + lh)*512 + qd*8;

    float4 st0, st1;
    half8  wcur[2][3], wnxt[2][3];

#define LOADX(ck) do {                                                        \
    st0 = *(const float4*)(xbase + (size_t)((ck)*64 + tc2)*NN);               \
    st1 = *(const float4*)(xbase + (size_t)((ck)*64 + 32 + tc2)*NN);          \
} while (0)
#define STOREX(p_) do {                                                       \
    xsT[p_][ti8*4+0][tc2]    = st0.x; xsT[p_][ti8*4+1][tc2]    = st0.y;       \
    xsT[p_][ti8*4+2][tc2]    = st0.z; xsT[p_][ti8*4+3][tc2]    = st0.w;       \
    xsT[p_][ti8*4+0][32+tc2] = st1.x; xsT[p_][ti8*4+1][32+tc2] = st1.y;       \
    xsT[p_][ti8*4+2][32+tc2] = st1.z; xsT[p_][ti8*4+3][32+tc2] = st1.w;       \
} while (0)
#define LOADW(ck, WD) do {                                                    \
    _Pragma("unroll")                                                         \
    for (int ks_ = 0; ks_ < 2; ks_++)                                         \
        _Pragma("unroll")                                                     \
        for (int ot_ = 0; ot_ < 3; ot_++)                                     \
            WD[ks_][ot_] = *(const half8*)(wbase + (size_t)(ot_*16)*512 + (ck)*64 + ks_*32); \
} while (0)

    LOADX(0); STOREX(0);
    LOADW(0, wcur);
    __syncthreads();

    #pragma unroll
    for (int ck = 0; ck < 8; ck++) {
        const int p = ck & 1;
        if (ck < 7) { LOADX(ck + 1); LOADW(ck + 1, wnxt); }

        #pragma unroll
        for (int ks = 0; ks < 2; ks++) {
            half8 xf[2];
            #pragma unroll
            for (int it = 0; it < 2; it++) {
                const float* xr = &xsT[p][it*16 + lh][ks*32 + qd*8];
                f32x4 xa = *(const f32x4*)xr;
                f32x4 xb = *(const f32x4*)(xr + 4);
                union { fp16x2 h2[4]; half8 h8; } u;
                u.h2[0] = __builtin_amdgcn_cvt_pkrtz(xa[0], xa[1]);
                u.h2[1] = __builtin_amdgcn_cvt_pkrtz(xa[2], xa[3]);
                u.h2[2] = __builtin_amdgcn_cvt_pkrtz(xb[0], xb[1]);
                u.h2[3] = __builtin_amdgcn_cvt_pkrtz(xb[2], xb[3]);
                xf[it] = u.h8;
            }
            #pragma unroll
            for (int ot = 0; ot < 3; ot++)
                #pragma unroll
                for (int it = 0; it < 2; it++)
                    acc[ot][it] = __builtin_amdgcn_mfma_f32_16x16x32_f16(wcur[ks][ot], xf[it], acc[ot][it], 0, 0, 0);
        }

        if (ck < 7) {
            STOREX(p ^ 1);
            #pragma unroll
            for (int ks_ = 0; ks_ < 2; ks_++)
                #pragma unroll
                for (int ot_ = 0; ot_ < 3; ot_++)
                    wcur[ks_][ot_] = wnxt[ks_][ot_];
        }
        __syncthreads();
    }
#undef LOADX
#undef STOREX
#undef LOADW

    #pragma unroll
    for (int ot = 0; ot < 3; ot++) {
        int g16 = w*3 + ot;          // 0..11
        int m   = g16 >> 2;
        int obase = (g16 & 3)*16 + qd*4;
        #pragma unroll
        for (int it = 0; it < 2; it++) {
            int ig = i0 + it*16 + lh;
            #pragma unroll
            for (int r = 0; r < 4; r++) {
                float v = acc[ot][it][r];
                int ol = obase + r;
                if (m == 0)       Kf[((size_t)b*NN + ig)*64 + ol] = (_Float16)v;
                else if (m == 1)  Qf[((size_t)b*NN + ig)*64 + ol] = (_Float16)v;
                else              Vt[((size_t)b*64 + ol)*NN + ig] = f2bf(v);
            }
        }
    }
}

// ---------------- Kernel 2: split-K flash attention, single-buffer LDS K/V ----------------
// grid 1024: (b, j-tile 64, split s of 1024 keys = 8 chunks of 128).
// Register-carried prefetch of chunk c+1; 40 KB LDS -> 4 blocks/CU.
__global__ __launch_bounds__(256) void attn_kernel(
    const _Float16* __restrict__ Kf, const _Float16* __restrict__ Qf,
    const unsigned short* __restrict__ Vt,
    _Float16* __restrict__ Po16, float* __restrict__ Pl)
{
    __shared__ __align__(16) unsigned short Kbuf[128*64];  // [i][d] swizzled 16B blocks
    __shared__ __align__(16) unsigned short Vbuf[64*128];  // [d][i] swizzled 16B blocks
    __shared__ __align__(16) unsigned short Psh[4][16*64]; // per-wave P bf16

    const int t    = threadIdx.x;
    const int wv   = t >> 6;
    const int lane = t & 63;
    const int lh   = lane & 15;
    const int qd   = lane >> 4;

    const int B   = blockIdx.x;
    const int xcd = B & 7;
    const int rr  = B >> 3;
    const int b   = xcd >> 1;
    const int jt  = (rr & 31)*2 + (xcd & 1);
    const int s   = rr >> 5;
    const int j0  = (jt << 6) + wv*16;

    const unsigned short* Kfu = (const unsigned short*)Kf;

    half8 qf0, qf1;
    {
        const size_t qb = ((size_t)b*NN + j0 + lh)*64 + qd*8;
        qf0 = *(const half8*)(Qf + qb);
        qf1 = *(const half8*)(Qf + qb + 32);
    }

    f32x4 o_acc[4];
    float l_r[4];
    #pragma unroll
    for (int dt = 0; dt < 4; dt++) { o_acc[dt][0]=0.f; o_acc[dt][1]=0.f; o_acc[dt][2]=0.f; o_acc[dt][3]=0.f; }
    #pragma unroll
    for (int r = 0; r < 4; r++) l_r[r] = 0.f;

    const int koff = s*1024;
    const int ki = t >> 3, kc = t & 7;
    const int vd = t >> 4, vc = t & 15;

#define LOADC(ck) do {                                                        \
    size_t kg = ((size_t)b*NN + koff + (ck)*128)*64;                          \
    size_t vg = (size_t)b*64*NN + koff + (ck)*128;                            \
    _Pragma("unroll")                                                         \
    for (int r_ = 0; r_ < 4; r_++) {                                          \
        kst[r_] = *(const us8*)(Kfu + kg + (size_t)(r_*32 + ki)*64 + kc*8);   \
        vst[r_] = *(const us8*)(Vt  + vg + (size_t)(r_*16 + vd)*NN + vc*8);   \
    } } while (0)

#define STOREC() do {                                                         \
    _Pragma("unroll")                                                         \
    for (int r_ = 0; r_ < 4; r_++) {                                          \
        int i_ = r_*32 + ki;                                                  \
        int d_ = r_*16 + vd;                                                  \
        *(us8*)(&Kbuf[i_*64  + ((kc ^ (i_ & 7))*8)])  = kst[r_];              \
        *(us8*)(&Vbuf[d_*128 + ((vc ^ (d_ & 15))*8)]) = vst[r_];              \
    } } while (0)

    us8 kst[4], vst[4];
    LOADC(0);
    STOREC();
    __syncthreads();

    for (int ck = 0; ck < 8; ck++) {
        if (ck < 7) LOADC(ck + 1);

        #pragma unroll
        for (int half = 0; half < 2; half++) {
            const unsigned short* Kb = &Kbuf[half*64*64];
            const unsigned short* Vb = &Vbuf[0];

            f32x4 sc[4];
            #pragma unroll
            for (int it = 0; it < 4; it++) {
                sc[it][0]=0.f; sc[it][1]=0.f; sc[it][2]=0.f; sc[it][3]=0.f;
                const unsigned short* kr = Kb + (it*16 + lh)*64;
                half8 k0 = *(const half8*)(kr + ((qd     ^ (lh & 7))*8));
                half8 k1 = *(const half8*)(kr + (((4+qd) ^ (lh & 7))*8));
                sc[it] = __builtin_amdgcn_mfma_f32_16x16x32_f16(qf0, k0, sc[it], 0,0,0);
                sc[it] = __builtin_amdgcn_mfma_f32_16x16x32_f16(qf1, k1, sc[it], 0,0,0);
            }

            // logits pre-scaled by log2e (folded into Wg) -> exp2
            #pragma unroll
            for (int it = 0; it < 4; it++)
                #pragma unroll
                for (int r = 0; r < 4; r++) {
                    float p_ = exp2f(sc[it][r]);
                    l_r[r] += p_;
                    int i_ = it*16 + lh;
                    int j_ = qd*4 + r;
                    Psh[wv][j_*64 + (((i_>>3) ^ (j_ & 7))*8) + (i_ & 7)] = f2bf(p_);
                }
            asm volatile("s_waitcnt lgkmcnt(0)" ::: "memory");

            short8 pf0 = *(const short8*)&Psh[wv][lh*64 + ((qd     ^ (lh & 7))*8)];
            short8 pf1 = *(const short8*)&Psh[wv][lh*64 + (((4+qd) ^ (lh & 7))*8)];

            #pragma unroll
            for (int dt = 0; dt < 4; dt++) {
                const unsigned short* vr = Vb + (dt*16 + lh)*128;
                short8 v0 = *(const short8*)(vr + (((half*8 + qd    ) ^ lh)*8));
                short8 v1 = *(const short8*)(vr + (((half*8 + 4 + qd) ^ lh)*8));
                o_acc[dt] = __builtin_amdgcn_mfma_f32_16x16x32_bf16(pf0, v0, o_acc[dt], 0,0,0);
                o_acc[dt] = __builtin_amdgcn_mfma_f32_16x16x32_bf16(pf1, v1, o_acc[dt], 0,0,0);
            }
        }

        __syncthreads();              // all reads of Kbuf/Vbuf done
        if (ck < 7) STOREC();
        __syncthreads();              // stores visible
    }
#undef LOADC
#undef STOREC

    float inv[4];
    #pragma unroll
    for (int r = 0; r < 4; r++) {
        float l = l_r[r];
        #pragma unroll
        for (int off = 1; off < 16; off <<= 1)
            l += __shfl_xor(l, off);
        l_r[r] = l;
        inv[r] = 1.0f / l;
    }
    const size_t pbase = ((size_t)(s*4 + b)*NN + j0);
    #pragma unroll
    for (int dt = 0; dt < 4; dt++)
        #pragma unroll
        for (int r = 0; r < 4; r++)
            Po16[(pbase + qd*4 + r)*64 + dt*16 + lh] = (_Float16)(o_acc[dt][r] * inv[r]);
    if (lh == 0) {
        #pragma unroll
        for (int r = 0; r < 4; r++)
            Pl[pbase + qd*4 + r] = l_r[r];
    }
}

// ---------------- Kernel 3: fused combine + output projection + residual ----------------
// grid 512: (b, j-chunk of 32). Inline split-K merge; LDS-transposed epilogue
// so out1/out2 stores and x residual loads are full dwordx4 (128B/8 lanes).
__global__ __launch_bounds__(256) void outproj_kernel(
    const _Float16* __restrict__ Po16, const float* __restrict__ Pl,
    const _Float16* __restrict__ Wv16,
    const float* __restrict__ x, const float* __restrict__ gamma,
    float* __restrict__ out1, float* __restrict__ out2)
{
    __shared__ float Osh[4][16][36];   // per-wave C-tile staging (36: 2-way banks only)
    const int t    = threadIdx.x;
    const int w    = t >> 6;
    const int lane = t & 63;
    const int lh   = lane & 15;
    const int qd   = lane >> 4;
    const int b    = blockIdx.x >> 7;
    const int j0   = (blockIdx.x & 127) << 5;
    const float g  = gamma[0];

    half8 sb[2][2];
    #pragma unroll
    for (int jt2 = 0; jt2 < 2; jt2++) {
        const int j = j0 + jt2*16 + lh;
        float os[16];
        #pragma unroll
        for (int k = 0; k < 16; k++) os[k] = 0.f;
        float lsum = 0.f;
        #pragma unroll
        for (int s = 0; s < 4; s++) {
            size_t base = ((size_t)(s*4 + b)*NN + j);
            half8 v0 = *(const half8*)(Po16 + base*64 + qd*8);
            half8 v1 = *(const half8*)(Po16 + base*64 + qd*8 + 32);
            float l = Pl[base];
            #pragma unroll
            for (int k = 0; k < 8; k++) {
                os[k]   = fmaf(l, (float)v0[k], os[k]);
                os[8+k] = fmaf(l, (float)v1[k], os[8+k]);
            }
            lsum += l;
        }
        float inv = 1.0f / lsum;
        union { fp16x2 h2[4]; half8 h8; } u0, u1;
        #pragma unroll
        for (int k = 0; k < 4; k++) {
            u0.h2[k] = __builtin_amdgcn_cvt_pkrtz(os[2*k]*inv,   os[2*k+1]*inv);
            u1.h2[k] = __builtin_amdgcn_cvt_pkrtz(os[8+2*k]*inv, os[8+2*k+1]*inv);
        }
        sb[jt2][0] = u0.h8;
        sb[jt2][1] = u1.h8;
    }

    const int o_loc8 = lane >> 3;          // 0..7
    const int j4     = (lane & 7) * 4;     // 0..28

    #pragma unroll 2
    for (int ot8 = 0; ot8 < 8; ot8++) {
        const int ot = w*8 + ot8;
        const size_t wbase = (size_t)(ot*16 + lh)*64 + qd*8;
        half8 a0 = *(const half8*)(Wv16 + wbase);
        half8 a1 = *(const half8*)(Wv16 + wbase + 32);

        f32x4 acc[2];
        #pragma unroll
        for (int jt2 = 0; jt2 < 2; jt2++) {
            acc[jt2][0]=0.f; acc[jt2][1]=0.f; acc[jt2][2]=0.f; acc[jt2][3]=0.f;
            acc[jt2] = __builtin_amdgcn_mfma_f32_16x16x32_f16(a0, sb[jt2][0], acc[jt2], 0, 0, 0);
            acc[jt2] = __builtin_amdgcn_mfma_f32_16x16x32_f16(a1, sb[jt2][1], acc[jt2], 0, 0, 0);
        }

        // stage C tile [o 16][j 32] in per-wave LDS
        #pragma unroll
        for (int jt2 = 0; jt2 < 2; jt2++)
            #pragma unroll
            for (int r = 0; r < 4; r++)
                Osh[w][qd*4 + r][jt2*16 + lh] = acc[jt2][r];
        asm volatile("s_waitcnt lgkmcnt(0)" ::: "memory");

        // read back transposed, vector stores
        #pragma unroll
        for (int rr2 = 0; rr2 < 2; rr2++) {
            const int o_loc = o_loc8 + 8*rr2;
            f32x4 v = *(const f32x4*)&Osh[w][o_loc][j4];
            const int o  = ot*16 + o_loc;
            const size_t idx = ((size_t)b*CC + o)*NN + j0 + j4;
            f32x4 xv = *(const f32x4*)(x + idx);
            *(f32x4*)(out2 + idx) = v;
            f32x4 r1;
            r1[0] = fmaf(g, v[0], xv[0]); r1[1] = fmaf(g, v[1], xv[1]);
            r1[2] = fmaf(g, v[2], xv[2]); r1[3] = fmaf(g, v[3], xv[3]);
            *(f32x4*)(out1 + idx) = r1;
        }
        asm volatile("s_waitcnt lgkmcnt(0)" ::: "memory");
    }
}

extern "C" void kernel_launch(void* const* d_in, const int* in_sizes, int n_in,
                              void* d_out, int out_size, void* d_ws, size_t ws_size,
                              hipStream_t stream) {
    const float* x     = (const float*)d_in[0];
    const float* Wf    = (const float*)d_in[1];
    const float* Wg    = (const float*)d_in[2];
    const float* Wh    = (const float*)d_in[3];
    const float* Wv    = (const float*)d_in[4];
    const float* gamma = (const float*)d_in[5];

    float* out1 = (float*)d_out;
    float* out2 = out1 + (size_t)BB*CC*NN;

    const size_t BND = (size_t)BB*NN*64;   // 1M elements
    char* wp = (char*)d_ws;
    _Float16*       Kf   = (_Float16*)wp;        wp += BND*2;   // 2 MB
    _Float16*       Qf   = (_Float16*)wp;        wp += BND*2;   // 2 MB
    unsigned short* Vt   = (unsigned short*)wp;  wp += BND*2;   // 2 MB
    _Float16*       Po16 = (_Float16*)wp;        wp += BND*4*2; // 8 MB (4 splits)
    float*          Pl   = (float*)wp;           wp += (size_t)4*BB*NN*4;  // 256 KB
    _Float16*       Wc16 = (_Float16*)wp;        wp += (size_t)192*512*2;
    _Float16*       Wv16 = (_Float16*)wp;

    prep_kernel<<<dim3(64), dim3(256), 0, stream>>>(Wf, Wg, Wh, Wv, Wc16, Wv16);
    proj_kernel<<<dim3(BB*128), dim3(256), 0, stream>>>(x, Wc16, Kf, Qf, Vt);
    attn_kernel<<<dim3(BB*256), dim3(256), 0, stream>>>(Kf, Qf, Vt, Po16, Pl);
    outproj_kernel<<<dim3(512), dim3(256), 0, stream>>>(Po16, Pl, Wv16, x, gamma, out1, out2);
}